// Round 1
// baseline (117.263 us; speedup 1.0000x reference)
//
#include <hip/hip_runtime.h>

// out[p, t, d] = weight[id[t], d] + EPS * mu[p, id[t], d]
// P=8, D=1024, V=50257, NT=B*S=8192
// One block (256 threads) per (t, p) pair; each lane handles one float4.

constexpr int   PD    = 1024;   // D
constexpr int   PP    = 8;      // P
constexpr float EPS   = 0.01f;

__global__ __launch_bounds__(256) void pe_gather_axpy(
    const int*   __restrict__ ids,     // [NT]
    const float* __restrict__ weight,  // [V, D]
    const float* __restrict__ mu,      // [P, V, D]
    float*       __restrict__ out,     // [P, NT, D]
    int NT, long long V)
{
    const int bid = blockIdx.x;
    const int t = bid >> 3;       // token index (t-major: 8 consecutive blocks
    const int p = bid & 7;        //   share the same weight row -> L2 reuse)
    if (t >= NT) return;

    const long long id = (long long)ids[t];

    const float4* __restrict__ w4 =
        reinterpret_cast<const float4*>(weight + id * PD);
    const float4* __restrict__ m4 =
        reinterpret_cast<const float4*>(mu + ((long long)p * V + id) * (long long)PD);
    float4* __restrict__ o4 =
        reinterpret_cast<float4*>(out + ((long long)p * NT + t) * (long long)PD);

    const int i = threadIdx.x;    // 256 lanes * 4 floats = 1024 = D
    const float4 w = w4[i];
    const float4 m = m4[i];
    float4 r;
    r.x = fmaf(EPS, m.x, w.x);
    r.y = fmaf(EPS, m.y, w.y);
    r.z = fmaf(EPS, m.z, w.z);
    r.w = fmaf(EPS, m.w, w.w);
    o4[i] = r;
}

extern "C" void kernel_launch(void* const* d_in, const int* in_sizes, int n_in,
                              void* d_out, int out_size, void* d_ws, size_t ws_size,
                              hipStream_t stream)
{
    const int*   ids    = (const int*)d_in[0];    // [B*S] (int per harness contract)
    const float* weight = (const float*)d_in[1];  // [V, D]
    const float* mu     = (const float*)d_in[2];  // [P, V, D]
    float*       out    = (float*)d_out;          // [P, B*S, D]

    const int NT = in_sizes[0];                       // 8192
    const long long V = (long long)in_sizes[1] / PD;  // 50257

    const int blocks = NT * PP;                       // 65536
    pe_gather_axpy<<<blocks, 256, 0, stream>>>(ids, weight, mu, out, NT, V);
}

// Round 3
// 93.070 us; speedup vs baseline: 1.2599x; 1.2599x over previous
//
#include <hip/hip_runtime.h>

// out[p, t, d] = weight[id[t], d] + EPS * mu[p, id[t], d]
// P=8, D=1024, V=50257, NT=B*S=8192
// One block (256 threads) per token; the P loop lives inside the block so the
// weight row is loaded ONCE into registers and reused for all 8 copies.
// Output is written with nontemporal stores (write-once stream, keep L2 for
// the gathered mu/weight rows).

constexpr int   PD  = 1024;   // D
constexpr int   PP  = 8;      // P
constexpr float EPS = 0.01f;

// clang-native 4-float vector: __builtin_nontemporal_store requires a real
// vector type, not HIP's HIP_vector_type class.
typedef float f4 __attribute__((ext_vector_type(4)));

__global__ __launch_bounds__(256) void pe_gather_axpy(
    const int*   __restrict__ ids,     // [NT]
    const float* __restrict__ weight,  // [V, D]
    const float* __restrict__ mu,      // [P, V, D]
    float*       __restrict__ out,     // [P, NT, D]
    int NT, long long V)
{
    const int t = blockIdx.x;
    if (t >= NT) return;

    const long long id = (long long)ids[t];
    const int i = threadIdx.x;            // 256 lanes * f4 = 1024 = D

    // Weight row: one f4 per lane, loaded once.
    const f4 w = reinterpret_cast<const f4*>(weight + id * PD)[i];

    // Issue all 8 mu loads first for maximum memory-level parallelism.
    const long long muRow  = id * (long long)PD;          // within one copy
    const long long muCopy = V * (long long)PD;           // stride between copies
    f4 m[PP];
    #pragma unroll
    for (int p = 0; p < PP; ++p) {
        m[p] = reinterpret_cast<const f4*>(mu + (long long)p * muCopy + muRow)[i];
    }

    const long long outTok  = (long long)t * PD;
    const long long outCopy = (long long)NT * PD;
    #pragma unroll
    for (int p = 0; p < PP; ++p) {
        f4 r = w + EPS * m[p];
        f4* o4 = reinterpret_cast<f4*>(out + (long long)p * outCopy + outTok);
        __builtin_nontemporal_store(r, &o4[i]);
    }
}

extern "C" void kernel_launch(void* const* d_in, const int* in_sizes, int n_in,
                              void* d_out, int out_size, void* d_ws, size_t ws_size,
                              hipStream_t stream)
{
    const int*   ids    = (const int*)d_in[0];    // [B*S]
    const float* weight = (const float*)d_in[1];  // [V, D]
    const float* mu     = (const float*)d_in[2];  // [P, V, D]
    float*       out    = (float*)d_out;          // [P, B*S, D]

    const int NT = in_sizes[0];                       // 8192
    const long long V = (long long)in_sizes[1] / PD;  // 50257

    pe_gather_axpy<<<NT, 256, 0, stream>>>(ids, weight, mu, out, NT, V);
}